// Round 13
// baseline (19204.785 us; speedup 1.0000x reference)
//
#include <hip/hip_runtime.h>
#include <math.h>

// Echo-state network: sequential scan with dense 2048x2048 matvec per step.
// R13 -- 8 time-chunks via TWO CHUNK-STREAMS PER BLOCK:
//  - R12 post-mortem: 8 chunks as 512 blocks is structurally infeasible --
//    W-in-registers would replicate 8 x 16.8MB = 134MB = the chip's entire
//    register file; launch_bounds(512,4)'s 128-reg cap can't even hold the
//    128-float W fragment. Diagnosis: register-file arithmetic, not tuning.
//  - Fix: 256 blocks x 512 thr (R11's PROVEN envelope: 1 block/CU,
//    launch_bounds(512,2), W frag 128 floats/lane pinned, 4 rows/wave).
//    Each block runs chunk c=blk&3 AND chunk c+4 in the same loop against
//    the SAME W registers. Rounds: 16384 -> 4096 (R11: 6144).
//  - Chunk 0 idles its first 2048 rounds (its pair chunk 4 keeps the block
//    busy), so EVERY chunk's true writes trail the colliding next-chunk
//    warm-up writes by 2048 lockstep rounds (~3.5ms skew margin).
//  - Parity bias-tag (even chunks store h+2, odd h+6; accept |v-bias|<=1.25)
//    disambiguates adjacent-chunk double-writes; c and c+4 share parity so
//    each block needs ONE bias constant. memset-0 / 0xAA poison = not-ready.
//  - Per-round machinery = R5/R11: block-cooperative poll (now 8 dwords/thr,
//    both streams, one straggler loop), publish to two LDS tiles, ONE
//    barrier, consume 2 x 8 ds_read_b128 vs register W, reduce/tanh/store.
//  - fc1/fc2 collapse: out = states_biased @ Mt + (c2b - bias_t * rm).

#define SS 16384
#define II 64
#define RR 2048
#define HH 128
#define OO 50
#define OP 64          // padded output dim
#define NCH 8          // time chunks (2 per block)
#define CSTEP 2048     // output steps per chunk
#define WUP 2048       // warm-up steps
#define NROUND (CSTEP + WUP)   // 4096 lockstep rounds
#define NBLK 256
#define NTHR 512
#define TT 16          // timesteps per block in out_kernel

static const size_t STATES_BYTES = (size_t)SS * RR * 4;        // 134217728
static const size_t MT_OFF  = STATES_BYTES;
static const size_t C2B_OFF = MT_OFF + (size_t)RR * OP * 4;    // +524288
static const size_t RM_OFF  = C2B_OFF + 256;
static const size_t RS_OFF  = RM_OFF + 256;
static const size_t WS_NEED = RS_OFF + 512 + 256;

// Opaque register pin for LOOP-INVARIANT values (W fragments) only.
#define PIN4(q) asm volatile("" : "+v"((q).x), "+v"((q).y), "+v"((q).z), "+v"((q).w))

// ---------------------------------------------------------------------------
// Persistent chunked scan, two streams per block.
// Block blk: chunkA = blk&3, chunkB = chunkA+4, brow = blk>>2.
// Wave w owns rows R0=brow*32+w*4 .. R0+3; lane l holds cols {4l+j+256m}.
// ---------------------------------------------------------------------------
__global__ __launch_bounds__(NTHR, 2)
void scan_kernel(const float* __restrict__ x,
                 const float* __restrict__ Win,
                 const float* __restrict__ W,
                 float* __restrict__ states)
{
    const int tid  = threadIdx.x;
    const int blk  = blockIdx.x;
    const int wave = tid >> 6;             // 0..7
    const int lane = tid & 63;
    const int cA   = blk & 3;              // stream A chunk (0..3)
    const int brow = blk >> 2;             // 0..63
    const int R0   = brow * 32 + wave * 4;

    const float bias = (cA & 1) ? 6.0f : 2.0f;   // cB=cA+4: same parity
    const int   g0A  = cA * CSTEP - WUP;         // chunk 0: -2048 (idle lead)
    const int   g0B  = (cA + 4) * CSTEP - WUP;
    const int   jA0  = (cA == 0) ? WUP : 0;      // first active round, stream A

    // W fragments: 4 rows x 8 float4 = 128 floats/lane, pinned.
    float4 wq[4][8];
#pragma unroll
    for (int r = 0; r < 4; ++r)
#pragma unroll
        for (int m = 0; m < 8; ++m) {
            wq[r][m] = *(const float4*)&W[(size_t)(R0 + r) * RR + 4 * lane + 256 * m];
            PIN4(wq[r][m]);
        }
    // Bias-fold: tw[r] = bias * sum of this lane's row-r fragment.
    float tw[4];
#pragma unroll
    for (int r = 0; r < 4; ++r) {
        float s = 0.f;
#pragma unroll
        for (int m = 0; m < 8; ++m)
            s += wq[r][m].x + wq[r][m].y + wq[r][m].z + wq[r][m].w;
        tw[r] = bias * s;
    }
    // Input projection fragments
    float win[4];
#pragma unroll
    for (int r = 0; r < 4; ++r)
        win[r] = Win[(size_t)(R0 + r) * II + lane];

    __shared__ float hbufA[2][RR];   // double-buffered biased h tiles
    __shared__ float hbufB[2][RR];

    float holdA = 0.f, holdB = 0.f;  // lane tracks row R0 + (lane&3)

    for (int j = 0; j < NROUND; ++j) {
        const int gA = g0A + j;
        const int gB = g0B + j;
        const bool activeA = (j >= jA0);
        const bool pollA   = (j > jA0);
        const bool pollB   = (j > 0);

        // x loads (stream-uniform predicates; no OOB reads)
        float xvA = 0.f, xvB = 0.f;
        if (activeA) xvA = x[(size_t)gA * II + lane];
        xvB = x[(size_t)gB * II + lane];

        float aA0 = win[0] * xvA, aA1 = win[1] * xvA,
              aA2 = win[2] * xvA, aA3 = win[3] * xvA;
        float aB0 = win[0] * xvB, aB1 = win[1] * xvB,
              aB2 = win[2] * xvB, aB3 = win[3] * xvB;

        // ---- combined poll: up to 8 independent dword loads ----
        float vA0 = bias, vA1 = bias, vA2 = bias, vA3 = bias;  // pass if !pollA
        float vB0 = bias, vB1 = bias, vB2 = bias, vB3 = bias;
        const float* hpA = states + (size_t)(gA - 1) * RR;
        const float* hpB = states + (size_t)(gB - 1) * RR;
        if (pollA) {
            vA0 = __hip_atomic_load(hpA + tid,        __ATOMIC_RELAXED, __HIP_MEMORY_SCOPE_AGENT);
            vA1 = __hip_atomic_load(hpA + tid + 512,  __ATOMIC_RELAXED, __HIP_MEMORY_SCOPE_AGENT);
            vA2 = __hip_atomic_load(hpA + tid + 1024, __ATOMIC_RELAXED, __HIP_MEMORY_SCOPE_AGENT);
            vA3 = __hip_atomic_load(hpA + tid + 1536, __ATOMIC_RELAXED, __HIP_MEMORY_SCOPE_AGENT);
        }
        if (pollB) {
            vB0 = __hip_atomic_load(hpB + tid,        __ATOMIC_RELAXED, __HIP_MEMORY_SCOPE_AGENT);
            vB1 = __hip_atomic_load(hpB + tid + 512,  __ATOMIC_RELAXED, __HIP_MEMORY_SCOPE_AGENT);
            vB2 = __hip_atomic_load(hpB + tid + 1024, __ATOMIC_RELAXED, __HIP_MEMORY_SCOPE_AGENT);
            vB3 = __hip_atomic_load(hpB + tid + 1536, __ATOMIC_RELAXED, __HIP_MEMORY_SCOPE_AGENT);
        }
        for (;;) {
            const bool rA0 = fabsf(vA0 - bias) <= 1.25f;
            const bool rA1 = fabsf(vA1 - bias) <= 1.25f;
            const bool rA2 = fabsf(vA2 - bias) <= 1.25f;
            const bool rA3 = fabsf(vA3 - bias) <= 1.25f;
            const bool rB0 = fabsf(vB0 - bias) <= 1.25f;
            const bool rB1 = fabsf(vB1 - bias) <= 1.25f;
            const bool rB2 = fabsf(vB2 - bias) <= 1.25f;
            const bool rB3 = fabsf(vB3 - bias) <= 1.25f;
            if (rA0 && rA1 && rA2 && rA3 && rB0 && rB1 && rB2 && rB3) break;
            if (!rA0) vA0 = __hip_atomic_load(hpA + tid,        __ATOMIC_RELAXED, __HIP_MEMORY_SCOPE_AGENT);
            if (!rA1) vA1 = __hip_atomic_load(hpA + tid + 512,  __ATOMIC_RELAXED, __HIP_MEMORY_SCOPE_AGENT);
            if (!rA2) vA2 = __hip_atomic_load(hpA + tid + 1024, __ATOMIC_RELAXED, __HIP_MEMORY_SCOPE_AGENT);
            if (!rA3) vA3 = __hip_atomic_load(hpA + tid + 1536, __ATOMIC_RELAXED, __HIP_MEMORY_SCOPE_AGENT);
            if (!rB0) vB0 = __hip_atomic_load(hpB + tid,        __ATOMIC_RELAXED, __HIP_MEMORY_SCOPE_AGENT);
            if (!rB1) vB1 = __hip_atomic_load(hpB + tid + 512,  __ATOMIC_RELAXED, __HIP_MEMORY_SCOPE_AGENT);
            if (!rB2) vB2 = __hip_atomic_load(hpB + tid + 1024, __ATOMIC_RELAXED, __HIP_MEMORY_SCOPE_AGENT);
            if (!rB3) vB3 = __hip_atomic_load(hpB + tid + 1536, __ATOMIC_RELAXED, __HIP_MEMORY_SCOPE_AGENT);
        }
        // Publish raw biased values (stride-512: 2-way bank alias, free)
        if (pollA) {
            float* sb = hbufA[j & 1];
            sb[tid] = vA0; sb[tid + 512] = vA1;
            sb[tid + 1024] = vA2; sb[tid + 1536] = vA3;
        }
        if (pollB) {
            float* sb = hbufB[j & 1];
            sb[tid] = vB0; sb[tid + 512] = vB1;
            sb[tid + 1024] = vB2; sb[tid + 1536] = vB3;
        }
        __syncthreads();           // the ONLY barrier per round

        // ---- consume stream A ----
        if (pollA) {
            aA0 -= tw[0]; aA1 -= tw[1]; aA2 -= tw[2]; aA3 -= tw[3];
            const float4* sq = (const float4*)hbufA[j & 1];
#pragma unroll
            for (int m = 0; m < 8; ++m) {
                const float4 q = sq[lane + 64 * m];
                aA0 += wq[0][m].x * q.x + wq[0][m].y * q.y
                     + wq[0][m].z * q.z + wq[0][m].w * q.w;
                aA1 += wq[1][m].x * q.x + wq[1][m].y * q.y
                     + wq[1][m].z * q.z + wq[1][m].w * q.w;
                aA2 += wq[2][m].x * q.x + wq[2][m].y * q.y
                     + wq[2][m].z * q.z + wq[2][m].w * q.w;
                aA3 += wq[3][m].x * q.x + wq[3][m].y * q.y
                     + wq[3][m].z * q.z + wq[3][m].w * q.w;
            }
        }
        // ---- consume stream B ----
        if (pollB) {
            aB0 -= tw[0]; aB1 -= tw[1]; aB2 -= tw[2]; aB3 -= tw[3];
            const float4* sq = (const float4*)hbufB[j & 1];
#pragma unroll
            for (int m = 0; m < 8; ++m) {
                const float4 q = sq[lane + 64 * m];
                aB0 += wq[0][m].x * q.x + wq[0][m].y * q.y
                     + wq[0][m].z * q.z + wq[0][m].w * q.w;
                aB1 += wq[1][m].x * q.x + wq[1][m].y * q.y
                     + wq[1][m].z * q.z + wq[1][m].w * q.w;
                aB2 += wq[2][m].x * q.x + wq[2][m].y * q.y
                     + wq[2][m].z * q.z + wq[2][m].w * q.w;
                aB3 += wq[3][m].x * q.x + wq[3][m].y * q.y
                     + wq[3][m].z * q.z + wq[3][m].w * q.w;
            }
        }

        // ---- reduce + tanh + store, stream A ----
        if (activeA) {
            const float own01 = (lane & 1) ? aA1 : aA0;
            const float oth01 = (lane & 1) ? aA0 : aA1;
            const float u01   = own01 + __shfl_xor(oth01, 1, 64);
            const float own23 = (lane & 1) ? aA3 : aA2;
            const float oth23 = (lane & 1) ? aA2 : aA3;
            const float u23   = own23 + __shfl_xor(oth23, 1, 64);
            const float own   = (lane & 2) ? u23 : u01;
            const float oth   = (lane & 2) ? u01 : u23;
            float a = own + __shfl_xor(oth, 2, 64);
#pragma unroll
            for (int off = 4; off <= 32; off <<= 1)
                a += __shfl_xor(a, off, 64);
            float u = fminf(fmaxf(a, -20.f), 20.f);
            const float e  = __expf(2.f * u);
            const float th = (e - 1.f) / (e + 1.f);
            const float hn = 0.5f * holdA + 0.5f * th;
            holdA = hn;
            if (lane < 4)
                __hip_atomic_store(&states[(size_t)gA * RR + R0 + lane], hn + bias,
                                   __ATOMIC_RELAXED, __HIP_MEMORY_SCOPE_AGENT);
        }
        // ---- reduce + tanh + store, stream B ----
        {
            const float own01 = (lane & 1) ? aB1 : aB0;
            const float oth01 = (lane & 1) ? aB0 : aB1;
            const float u01   = own01 + __shfl_xor(oth01, 1, 64);
            const float own23 = (lane & 1) ? aB3 : aB2;
            const float oth23 = (lane & 1) ? aB2 : aB3;
            const float u23   = own23 + __shfl_xor(oth23, 1, 64);
            const float own   = (lane & 2) ? u23 : u01;
            const float oth   = (lane & 2) ? u01 : u23;
            float a = own + __shfl_xor(oth, 2, 64);
#pragma unroll
            for (int off = 4; off <= 32; off <<= 1)
                a += __shfl_xor(a, off, 64);
            float u = fminf(fmaxf(a, -20.f), 20.f);
            const float e  = __expf(2.f * u);
            const float th = (e - 1.f) / (e + 1.f);
            const float hn = 0.5f * holdB + 0.5f * th;
            holdB = hn;
            if (lane < 4)
                __hip_atomic_store(&states[(size_t)gB * RR + R0 + lane], hn + bias,
                                   __ATOMIC_RELAXED, __HIP_MEMORY_SCOPE_AGENT);
        }
    }
}

// ---------------------------------------------------------------------------
// rowsum of fc1_w rows: rs[h] = sum_r fc1_w[h][r]
// ---------------------------------------------------------------------------
__global__ void k_rowsum(const float* __restrict__ fc1w, float* __restrict__ rs)
{
    const int h = blockIdx.x;
    const int tid = threadIdx.x;
    float a = 0.f;
    for (int r = tid; r < RR; r += 256) a += fc1w[(size_t)h * RR + r];
#pragma unroll
    for (int off = 1; off <= 32; off <<= 1) a += __shfl_xor(a, off, 64);
    __shared__ float red[4];
    if ((tid & 63) == 0) red[tid >> 6] = a;
    __syncthreads();
    if (tid == 0) rs[h] = red[0] + red[1] + red[2] + red[3];
}

// ---------------------------------------------------------------------------
// Mt[r][o] = sum_h fc2_w[o][h] * fc1_w[h][r]   (o padded to 64, zeros)
// ---------------------------------------------------------------------------
__global__ void k_mt(const float* __restrict__ fc1w,
                     const float* __restrict__ fc2w,
                     float* __restrict__ Mt)
{
    __shared__ float w2[OO][HH + 1];
    const int o = threadIdx.x;         // 64
    const int r = blockIdx.x;          // 2048
    for (int i = o; i < OO * HH; i += 64) w2[i / HH][i % HH] = fc2w[i];
    __syncthreads();
    float a = 0.f;
    if (o < OO) {
        for (int h = 0; h < HH; ++h)
            a += w2[o][h] * fc1w[(size_t)h * RR + r];
    }
    Mt[r * OP + o] = a;
}

// ---------------------------------------------------------------------------
// c2b[o] = fc2_b[o] + sum_h fc2_w[o][h]*fc1_b[h];  rm[o] = sum_h fc2w*rs[h]
// ---------------------------------------------------------------------------
__global__ void k_cc(const float* __restrict__ fc2w,
                     const float* __restrict__ fc2b,
                     const float* __restrict__ fc1b,
                     const float* __restrict__ rs,
                     float* __restrict__ c2b,
                     float* __restrict__ rm)
{
    const int o = threadIdx.x;  // 64
    float a = 0.f, b = 0.f;
    if (o < OO) {
        for (int h = 0; h < HH; ++h) {
            a += fc2w[o * HH + h] * fc1b[h];
            b += fc2w[o * HH + h] * rs[h];
        }
        a += fc2b[o];
    }
    c2b[o] = a;
    rm[o]  = b;
}

// ---------------------------------------------------------------------------
// out[t][o] = sum_r Mt[r][o] * states_biased[t][r] + c2b[o] - bias_t*rm[o]
// ---------------------------------------------------------------------------
__global__ __launch_bounds__(256)
void out_kernel(const float* __restrict__ sb,
                const float* __restrict__ Mt,
                const float* __restrict__ c2b,
                const float* __restrict__ rm,
                float* __restrict__ out)
{
    const int tid = threadIdx.x;
    const int o   = tid & 63;
    const int tl  = tid >> 6;          // 0..3
    const int t0  = blockIdx.x * TT;
    const float bias = ((t0 >> 11) & 1) ? 6.0f : 2.0f;  // chunk parity (CSTEP=2048)
    float acc[4] = {0.f, 0.f, 0.f, 0.f};
    const float* s0 = sb + (size_t)t0 * RR;

    for (int r = 0; r < RR; r += 4) {
        float4 sv0 = *(const float4*)(s0 + (size_t)(tl + 0)  * RR + r);
        float4 sv1 = *(const float4*)(s0 + (size_t)(tl + 4)  * RR + r);
        float4 sv2 = *(const float4*)(s0 + (size_t)(tl + 8)  * RR + r);
        float4 sv3 = *(const float4*)(s0 + (size_t)(tl + 12) * RR + r);
        float m0 = Mt[(r + 0) * OP + o];
        float m1 = Mt[(r + 1) * OP + o];
        float m2 = Mt[(r + 2) * OP + o];
        float m3 = Mt[(r + 3) * OP + o];
        acc[0] += m0 * sv0.x + m1 * sv0.y + m2 * sv0.z + m3 * sv0.w;
        acc[1] += m0 * sv1.x + m1 * sv1.y + m2 * sv1.z + m3 * sv1.w;
        acc[2] += m0 * sv2.x + m1 * sv2.y + m2 * sv2.z + m3 * sv2.w;
        acc[3] += m0 * sv3.x + m1 * sv3.y + m2 * sv3.z + m3 * sv3.w;
    }
    if (o < OO) {
        const float cc = c2b[o] - bias * rm[o];
#pragma unroll
        for (int m = 0; m < 4; ++m) {
            const int t = t0 + tl + 4 * m;
            out[(size_t)t * OO + o] = acc[m] + cc;
        }
    }
}

extern "C" void kernel_launch(void* const* d_in, const int* in_sizes, int n_in,
                              void* d_out, int out_size, void* d_ws, size_t ws_size,
                              hipStream_t stream)
{
    const float* x    = (const float*)d_in[0];
    const float* Win  = (const float*)d_in[1];
    const float* W    = (const float*)d_in[2];
    const float* fc1w = (const float*)d_in[3];
    const float* fc1b = (const float*)d_in[4];
    const float* fc2w = (const float*)d_in[5];
    const float* fc2b = (const float*)d_in[6];
    float* out = (float*)d_out;

    if (ws_size < WS_NEED) return;

    char*  ws     = (char*)d_ws;
    float* states = (float*)ws;
    float* Mt     = (float*)(ws + MT_OFF);
    float* c2b    = (float*)(ws + C2B_OFF);
    float* rm     = (float*)(ws + RM_OFF);
    float* rs     = (float*)(ws + RS_OFF);

    // Sentinel init: 0.0f is outside both bias ranges -> "not ready".
    hipMemsetAsync(states, 0, STATES_BYTES, stream);

    k_rowsum<<<HH, 256, 0, stream>>>(fc1w, rs);
    k_mt<<<RR, 64, 0, stream>>>(fc1w, fc2w, Mt);
    k_cc<<<1, 64, 0, stream>>>(fc2w, fc2b, fc1b, rs, c2b, rm);

    scan_kernel<<<NBLK, NTHR, 0, stream>>>(x, Win, W, states);

    out_kernel<<<SS / TT, 256, 0, stream>>>(states, Mt, c2b, rm, out);
}

// Round 14
// 7530.161 us; speedup vs baseline: 2.5504x; 2.5504x over previous
//
#include <hip/hip_runtime.h>
#include <math.h>

// Echo-state network: sequential scan with dense 2048x2048 matvec per step.
// R14 -- R11's proven single-stream structure, rounds squeezed:
//  - R13 lesson: two chunk-streams per block inflates the round constant
//    2.8x (serialized double work + global convoy through shared blocks).
//    Reverted to R11: 4 chunks x 64 blocks, 256 blocks x 512 thr (1/CU),
//    4 rows/wave, W frag 128 floats/lane pinned, launch_bounds(512,2).
//  - NEW: warm-up 2048 -> 1024 (R11's absmax was bit-identical to
//    unchunked; mean-field contraction ~0.82/step makes 1024 ~ e^-200) and
//    UNEVEN chunks to equalize finish: chunk0 = 4864 outputs (no warm-up),
//    chunks1-3 = 3840 outputs + 1024 warm-up -> uniform 4864 rounds (-21%).
//    Boundaries 4864/8704/12544 (all %16==0 for out_kernel tiles).
//  - NEW: XCD-affinity remap: chunk = (blk&7)>>1, brow = (blk>>3)*2+(blk&1)
//    puts each chunk's 64 blocks on XCD pair {2c,2c+1} under blockIdx%8
//    round-robin dispatch -> intra-chunk poll locality. Perf-only heuristic.
//  - Parity bias-tag unchanged: even chunks store h+2, odd h+6; poll accepts
//    |v-bias|<=1.25; memset-0 / 0xAA poison read not-ready; warm-up writes
//    of chunk c+1 trail chunk c's true writes by ~3800 lockstep rounds.
//  - Per-round machinery = R5/R11: block-cooperative poll (4 dwords/thr),
//    straggler-only retry, publish to LDS, ONE barrier, consume
//    8 x ds_read_b128 vs register W, 7-shfl reduce, tanh, store.
//  - fc1/fc2 collapse: out = states_biased @ Mt + (c2b - bias_t * rm).

#define SS 16384
#define II 64
#define RR 2048
#define HH 128
#define OO 50
#define OP 64          // padded output dim
#define NROUND 4864    // rounds per chunk (uniform)
#define C0LEN 4864     // chunk 0 output length
#define CLEN 3840      // chunks 1-3 output length
#define WUP 1024       // warm-up steps for chunks 1-3
#define NBLK 256
#define NTHR 512
#define TT 16          // timesteps per block in out_kernel

static const size_t STATES_BYTES = (size_t)SS * RR * 4;        // 134217728
static const size_t MT_OFF  = STATES_BYTES;
static const size_t C2B_OFF = MT_OFF + (size_t)RR * OP * 4;    // +524288
static const size_t RM_OFF  = C2B_OFF + 256;
static const size_t RS_OFF  = RM_OFF + 256;
static const size_t WS_NEED = RS_OFF + 512 + 256;

// Opaque register pin for LOOP-INVARIANT values (W fragments) only.
#define PIN4(q) asm volatile("" : "+v"((q).x), "+v"((q).y), "+v"((q).z), "+v"((q).w))

// ---------------------------------------------------------------------------
// Persistent chunked scan. chunk = (blk&7)>>1 (XCD-pair affinity),
// brow = (blk>>3)*2 + (blk&1). Wave w owns rows R0=brow*32+w*4 .. R0+3;
// lane l holds cols {4l+j+256m} of its 4 rows.
// ---------------------------------------------------------------------------
__global__ __launch_bounds__(NTHR, 2)
void scan_kernel(const float* __restrict__ x,
                 const float* __restrict__ Win,
                 const float* __restrict__ W,
                 float* __restrict__ states)
{
    const int tid   = threadIdx.x;
    const int blk   = blockIdx.x;
    const int wave  = tid >> 6;             // 0..7
    const int lane  = tid & 63;
    const int chunk = (blk & 7) >> 1;       // XCD pair {2c, 2c+1}
    const int brow  = ((blk >> 3) << 1) | (blk & 1);   // 0..63
    const int R0    = brow * 32 + wave * 4;

    const float bias = (chunk & 1) ? 6.0f : 2.0f;
    // chunk 0: [0, 4864) no warm-up; chunk c>=1: g0 = 4864+(c-1)*3840-1024
    const int g0 = (chunk == 0) ? 0 : (C0LEN + (chunk - 1) * CLEN - WUP);

    // W fragments: 4 rows x 8 float4 = 128 floats/lane, pinned.
    float4 wq[4][8];
#pragma unroll
    for (int r = 0; r < 4; ++r)
#pragma unroll
        for (int m = 0; m < 8; ++m) {
            wq[r][m] = *(const float4*)&W[(size_t)(R0 + r) * RR + 4 * lane + 256 * m];
            PIN4(wq[r][m]);
        }
    // Bias-fold: tw[r] = bias * sum of this lane's row-r fragment.
    float tw[4];
#pragma unroll
    for (int r = 0; r < 4; ++r) {
        float s = 0.f;
#pragma unroll
        for (int m = 0; m < 8; ++m)
            s += wq[r][m].x + wq[r][m].y + wq[r][m].z + wq[r][m].w;
        tw[r] = bias * s;
    }
    // Input projection fragments
    float win[4];
#pragma unroll
    for (int r = 0; r < 4; ++r)
        win[r] = Win[(size_t)(R0 + r) * II + lane];

    __shared__ float hbuf[2][RR];   // double-buffered biased h tile

    float hold = 0.f;               // lane tracks row R0 + (lane&3)

    for (int j = 0; j < NROUND; ++j) {
        const int g = g0 + j;
        const float xv = x[(size_t)g * II + lane];
        float a0 = win[0] * xv;
        float a1 = win[1] * xv;
        float a2 = win[2] * xv;
        float a3 = win[3] * xv;

        if (j > 0) {
            const float* hp = states + (size_t)(g - 1) * RR;
            float* sb = hbuf[(j - 1) & 1];
            // First pass: 4 coalesced dword poll loads per thread.
            float v0 = __hip_atomic_load(hp + tid,
                                         __ATOMIC_RELAXED, __HIP_MEMORY_SCOPE_AGENT);
            float v1 = __hip_atomic_load(hp + tid + 512,
                                         __ATOMIC_RELAXED, __HIP_MEMORY_SCOPE_AGENT);
            float v2 = __hip_atomic_load(hp + tid + 1024,
                                         __ATOMIC_RELAXED, __HIP_MEMORY_SCOPE_AGENT);
            float v3 = __hip_atomic_load(hp + tid + 1536,
                                         __ATOMIC_RELAXED, __HIP_MEMORY_SCOPE_AGENT);
            // Parity-range readiness: accept only my chunk's bias range.
            for (;;) {
                const bool r0 = fabsf(v0 - bias) <= 1.25f;
                const bool r1 = fabsf(v1 - bias) <= 1.25f;
                const bool r2 = fabsf(v2 - bias) <= 1.25f;
                const bool r3 = fabsf(v3 - bias) <= 1.25f;
                if (r0 && r1 && r2 && r3) break;
                if (!r0) v0 = __hip_atomic_load(hp + tid,
                                __ATOMIC_RELAXED, __HIP_MEMORY_SCOPE_AGENT);
                if (!r1) v1 = __hip_atomic_load(hp + tid + 512,
                                __ATOMIC_RELAXED, __HIP_MEMORY_SCOPE_AGENT);
                if (!r2) v2 = __hip_atomic_load(hp + tid + 1024,
                                __ATOMIC_RELAXED, __HIP_MEMORY_SCOPE_AGENT);
                if (!r3) v3 = __hip_atomic_load(hp + tid + 1536,
                                __ATOMIC_RELAXED, __HIP_MEMORY_SCOPE_AGENT);
            }
            // Publish raw biased values (stride-512: 2-way bank alias, free)
            sb[tid]        = v0;
            sb[tid + 512]  = v1;
            sb[tid + 1024] = v2;
            sb[tid + 1536] = v3;
            __syncthreads();           // the ONLY barrier per round

            a0 -= tw[0]; a1 -= tw[1]; a2 -= tw[2]; a3 -= tw[3];

            // Consume: 8 x ds_read_b128 vs register-held W (4 rows).
            const float4* sq = (const float4*)sb;
#pragma unroll
            for (int m = 0; m < 8; ++m) {
                const float4 q = sq[lane + 64 * m];
                a0 += wq[0][m].x * q.x + wq[0][m].y * q.y
                    + wq[0][m].z * q.z + wq[0][m].w * q.w;
                a1 += wq[1][m].x * q.x + wq[1][m].y * q.y
                    + wq[1][m].z * q.z + wq[1][m].w * q.w;
                a2 += wq[2][m].x * q.x + wq[2][m].y * q.y
                    + wq[2][m].z * q.z + wq[2][m].w * q.w;
                a3 += wq[3][m].x * q.x + wq[3][m].y * q.y
                    + wq[3][m].z * q.z + wq[3][m].w * q.w;
            }
        }

        // Reduce 4 rows: 2 fold stages + 4-level butterfly (7 shfls).
        {
            const float own01 = (lane & 1) ? a1 : a0;
            const float oth01 = (lane & 1) ? a0 : a1;
            const float u01   = own01 + __shfl_xor(oth01, 1, 64);
            const float own23 = (lane & 1) ? a3 : a2;
            const float oth23 = (lane & 1) ? a2 : a3;
            const float u23   = own23 + __shfl_xor(oth23, 1, 64);
            const float own   = (lane & 2) ? u23 : u01;
            const float oth   = (lane & 2) ? u01 : u23;
            float a = own + __shfl_xor(oth, 2, 64);
#pragma unroll
            for (int off = 4; off <= 32; off <<= 1)
                a += __shfl_xor(a, off, 64);
            // tanh + leaky update for row R0 + (lane&3)
            float u = fminf(fmaxf(a, -20.f), 20.f);
            const float e  = __expf(2.f * u);
            const float th = (e - 1.f) / (e + 1.f);
            const float hn = 0.5f * hold + 0.5f * th;
            hold = hn;
            if (lane < 4)
                __hip_atomic_store(&states[(size_t)g * RR + R0 + lane], hn + bias,
                                   __ATOMIC_RELAXED, __HIP_MEMORY_SCOPE_AGENT);
        }
    }
}

// ---------------------------------------------------------------------------
// rowsum of fc1_w rows: rs[h] = sum_r fc1_w[h][r]
// ---------------------------------------------------------------------------
__global__ void k_rowsum(const float* __restrict__ fc1w, float* __restrict__ rs)
{
    const int h = blockIdx.x;
    const int tid = threadIdx.x;
    float a = 0.f;
    for (int r = tid; r < RR; r += 256) a += fc1w[(size_t)h * RR + r];
#pragma unroll
    for (int off = 1; off <= 32; off <<= 1) a += __shfl_xor(a, off, 64);
    __shared__ float red[4];
    if ((tid & 63) == 0) red[tid >> 6] = a;
    __syncthreads();
    if (tid == 0) rs[h] = red[0] + red[1] + red[2] + red[3];
}

// ---------------------------------------------------------------------------
// Mt[r][o] = sum_h fc2_w[o][h] * fc1_w[h][r]   (o padded to 64, zeros)
// ---------------------------------------------------------------------------
__global__ void k_mt(const float* __restrict__ fc1w,
                     const float* __restrict__ fc2w,
                     float* __restrict__ Mt)
{
    __shared__ float w2[OO][HH + 1];
    const int o = threadIdx.x;         // 64
    const int r = blockIdx.x;          // 2048
    for (int i = o; i < OO * HH; i += 64) w2[i / HH][i % HH] = fc2w[i];
    __syncthreads();
    float a = 0.f;
    if (o < OO) {
        for (int h = 0; h < HH; ++h)
            a += w2[o][h] * fc1w[(size_t)h * RR + r];
    }
    Mt[r * OP + o] = a;
}

// ---------------------------------------------------------------------------
// c2b[o] = fc2_b[o] + sum_h fc2_w[o][h]*fc1_b[h];  rm[o] = sum_h fc2w*rs[h]
// ---------------------------------------------------------------------------
__global__ void k_cc(const float* __restrict__ fc2w,
                     const float* __restrict__ fc2b,
                     const float* __restrict__ fc1b,
                     const float* __restrict__ rs,
                     float* __restrict__ c2b,
                     float* __restrict__ rm)
{
    const int o = threadIdx.x;  // 64
    float a = 0.f, b = 0.f;
    if (o < OO) {
        for (int h = 0; h < HH; ++h) {
            a += fc2w[o * HH + h] * fc1b[h];
            b += fc2w[o * HH + h] * rs[h];
        }
        a += fc2b[o];
    }
    c2b[o] = a;
    rm[o]  = b;
}

// ---------------------------------------------------------------------------
// out[t][o] = sum_r Mt[r][o] * states_biased[t][r] + c2b[o] - bias_t*rm[o]
// Chunk boundaries 4864/8704/12544 are %16==0, so a 16-step tile is
// chunk-uniform.
// ---------------------------------------------------------------------------
__global__ __launch_bounds__(256)
void out_kernel(const float* __restrict__ sb,
                const float* __restrict__ Mt,
                const float* __restrict__ c2b,
                const float* __restrict__ rm,
                float* __restrict__ out)
{
    const int tid = threadIdx.x;
    const int o   = tid & 63;
    const int tl  = tid >> 6;          // 0..3
    const int t0  = blockIdx.x * TT;
    const int chunk = (t0 < C0LEN) ? 0 : (1 + (t0 - C0LEN) / CLEN);
    const float bias = (chunk & 1) ? 6.0f : 2.0f;
    float acc[4] = {0.f, 0.f, 0.f, 0.f};
    const float* s0 = sb + (size_t)t0 * RR;

    for (int r = 0; r < RR; r += 4) {
        float4 sv0 = *(const float4*)(s0 + (size_t)(tl + 0)  * RR + r);
        float4 sv1 = *(const float4*)(s0 + (size_t)(tl + 4)  * RR + r);
        float4 sv2 = *(const float4*)(s0 + (size_t)(tl + 8)  * RR + r);
        float4 sv3 = *(const float4*)(s0 + (size_t)(tl + 12) * RR + r);
        float m0 = Mt[(r + 0) * OP + o];
        float m1 = Mt[(r + 1) * OP + o];
        float m2 = Mt[(r + 2) * OP + o];
        float m3 = Mt[(r + 3) * OP + o];
        acc[0] += m0 * sv0.x + m1 * sv0.y + m2 * sv0.z + m3 * sv0.w;
        acc[1] += m0 * sv1.x + m1 * sv1.y + m2 * sv1.z + m3 * sv1.w;
        acc[2] += m0 * sv2.x + m1 * sv2.y + m2 * sv2.z + m3 * sv2.w;
        acc[3] += m0 * sv3.x + m1 * sv3.y + m2 * sv3.z + m3 * sv3.w;
    }
    if (o < OO) {
        const float cc = c2b[o] - bias * rm[o];
#pragma unroll
        for (int m = 0; m < 4; ++m) {
            const int t = t0 + tl + 4 * m;
            out[(size_t)t * OO + o] = acc[m] + cc;
        }
    }
}

extern "C" void kernel_launch(void* const* d_in, const int* in_sizes, int n_in,
                              void* d_out, int out_size, void* d_ws, size_t ws_size,
                              hipStream_t stream)
{
    const float* x    = (const float*)d_in[0];
    const float* Win  = (const float*)d_in[1];
    const float* W    = (const float*)d_in[2];
    const float* fc1w = (const float*)d_in[3];
    const float* fc1b = (const float*)d_in[4];
    const float* fc2w = (const float*)d_in[5];
    const float* fc2b = (const float*)d_in[6];
    float* out = (float*)d_out;

    if (ws_size < WS_NEED) return;

    char*  ws     = (char*)d_ws;
    float* states = (float*)ws;
    float* Mt     = (float*)(ws + MT_OFF);
    float* c2b    = (float*)(ws + C2B_OFF);
    float* rm     = (float*)(ws + RM_OFF);
    float* rs     = (float*)(ws + RS_OFF);

    // Sentinel init: 0.0f is outside both bias ranges -> "not ready".
    hipMemsetAsync(states, 0, STATES_BYTES, stream);

    k_rowsum<<<HH, 256, 0, stream>>>(fc1w, rs);
    k_mt<<<RR, 64, 0, stream>>>(fc1w, fc2w, Mt);
    k_cc<<<1, 64, 0, stream>>>(fc2w, fc2b, fc1b, rs, c2b, rm);

    scan_kernel<<<NBLK, NTHR, 0, stream>>>(x, Win, W, states);

    out_kernel<<<SS / TT, 256, 0, stream>>>(states, Mt, c2b, rm, out);
}